// Round 6
// baseline (1028.861 us; speedup 1.0000x reference)
//
#include <hip/hip_runtime.h>

typedef unsigned int u32;
typedef unsigned short u16;
typedef __attribute__((ext_vector_type(8))) short bf16x8;
typedef __attribute__((ext_vector_type(4))) float f32x4;

#define Bb 4
#define Nn 50000
#define Dd 128
#define Rr 200
#define BN (Bb*Nn)
#define MAXDEG 32
#define LDW 136          // u16 row stride inside a wave slab (272 B, 16B-aligned)
#define SLAB 4352        // u16 per wave slab: 2 tiles x 16 rows x 136

// ---------- scalar helpers ----------
__device__ __forceinline__ float bfs(u16 u) { return __uint_as_float(((u32)u) << 16); }
__device__ __forceinline__ float bflo(u32 u) { return __uint_as_float(u << 16); }
__device__ __forceinline__ float bfhi(u32 u) { return __uint_as_float(u & 0xffff0000u); }
__device__ __forceinline__ u16 f2bf(float f) {
    u32 x = __float_as_uint(f);
    return (u16)((x + 0x7fffu + ((x >> 16) & 1u)) >> 16);
}
template<bool BF>
__device__ __forceinline__ float ld1(const void* p, int i) {
    if (BF) return bfs(((const u16*)p)[i]);
    else    return ((const float*)p)[i];
}

// ---------- dtype probe: bf16-packed vs f32 ----------
__global__ void k_probe(const u32* __restrict__ q, int* __restrict__ flag) {
    int t = threadIdx.x;
    u32 w = q[t];
    int e = (int)((w >> 7) & 0xffu);
    bool plaus = (e >= 100 && e <= 150);
    unsigned long long m = __ballot(plaus);
    if (t == 0) flag[0] = (__popcll(m) >= 56) ? 1 : 0;
}

// ---------- prep: split weights to bf16 hi/lo, f32 copies of small tensors ----------
__global__ __launch_bounds__(256) void k_wprep(
    const void* Ws, const void* w1, const void* w2,
    const void* b1, const void* b2, const void* wattn, const void* rela,
    u16* WsH, u16* WsL, u16* w1H, u16* w1L, u16* w2H, u16* w2L,
    float* b1f, float* b2f, float* wattnf, float* relaf, const int* flag) {
    bool bf = (*flag != 0);
    int i = blockIdx.x * 256 + threadIdx.x;
    if (i < 16384) {
        float x = bf ? bfs(((const u16*)Ws)[i]) : ((const float*)Ws)[i];
        u16 h = f2bf(x); WsH[i] = h; WsL[i] = f2bf(x - bfs(h));
    } else if (i < 32768) {
        int j = i - 16384;
        float x = bf ? bfs(((const u16*)w1)[j]) : ((const float*)w1)[j];
        u16 h = f2bf(x); w1H[j] = h; w1L[j] = f2bf(x - bfs(h));
    } else if (i < 49152) {
        int j = i - 32768;
        float x = bf ? bfs(((const u16*)w2)[j]) : ((const float*)w2)[j];
        u16 h = f2bf(x); w2H[j] = h; w2L[j] = f2bf(x - bfs(h));
    } else if (i < 49152 + 128) {
        int j = i - 49152;
        b1f[j] = bf ? bfs(((const u16*)b1)[j]) : ((const float*)b1)[j];
    } else if (i < 49152 + 256) {
        int j = i - 49152 - 128;
        b2f[j] = bf ? bfs(((const u16*)b2)[j]) : ((const float*)b2)[j];
    } else if (i < 49152 + 384) {
        int j = i - 49152 - 256;
        wattnf[j] = bf ? bfs(((const u16*)wattn)[j]) : ((const float*)wattn)[j];
    } else if (i < 49152 + 384 + 25600) {
        int j = i - 49152 - 384;
        relaf[j] = bf ? bfs(((const u16*)rela)[j]) : ((const float*)rela)[j];
    }
}

// ---------- wrq[b*R+r][a] = Wr.rela_r + Wqr.query_b + bias (tiny, f32 VALU) ----------
template<bool BF>
__device__ __forceinline__ float dotrow1(const void* W, int row, const float* s) {
    float acc = 0.f;
    if (BF) {
        const uint4* wv = (const uint4*)((const u16*)W + row * Dd);
#pragma unroll
        for (int k = 0; k < 16; k++) {
            uint4 u = wv[k];
            acc += bflo(u.x)*s[k*8+0] + bfhi(u.x)*s[k*8+1]
                 + bflo(u.y)*s[k*8+2] + bfhi(u.y)*s[k*8+3]
                 + bflo(u.z)*s[k*8+4] + bfhi(u.z)*s[k*8+5]
                 + bflo(u.w)*s[k*8+6] + bfhi(u.w)*s[k*8+7];
        }
    } else {
        const float4* wv = (const float4*)((const float*)W + row * Dd);
#pragma unroll
        for (int k = 0; k < 32; k++) {
            float4 u = wv[k];
            acc += u.x*s[4*k] + u.y*s[4*k+1] + u.z*s[4*k+2] + u.w*s[4*k+3];
        }
    }
    return acc;
}
template<bool BF>
__device__ void k_wrq_body(const void* Wr, const void* Wqr, const void* bias,
                           const void* rela, const void* query, float* wrq, float* s) {
    int br = blockIdx.x;
    int b = br / Rr, r = br % Rr;
    int a = threadIdx.x;
    s[a]      = ld1<BF>(rela,  r * Dd + a);
    s[Dd + a] = ld1<BF>(query, b * Dd + a);
    __syncthreads();
    wrq[br * Dd + a] = ld1<BF>(bias, a) + dotrow1<BF>(Wr, a, s) + dotrow1<BF>(Wqr, a, s + Dd);
}
__global__ __launch_bounds__(128) void k_wrq(const void* Wr, const void* Wqr, const void* bias,
                                             const void* rela, const void* query, float* wrq,
                                             const int* flag) {
    __shared__ float s[2 * Dd];
    if (*flag) k_wrq_body<true>(Wr, Wqr, bias, rela, query, wrq, s);
    else       k_wrq_body<false>(Wr, Wqr, bias, rela, query, wrq, s);
}

// ---------- hs = hidden @ Ws^T via split-bf16 MFMA (wave-private slab, no barriers) ----------
template<bool BF>
__device__ void hs_body(const void* hidden, const u16* WsH, const u16* WsL, u16* hs,
                        u16* __restrict__ Smh) {
    int t = threadIdx.x, lane = t & 63;
    int m16 = lane & 15, quad = lane >> 4;
    int w = t >> 6;
    int base = blockIdx.x * 64 + w * 16;
    u16* Sml = Smh + 16 * LDW;

    if (BF) {
        const u16* src = (const u16*)hidden + (size_t)base * Dd;
#pragma unroll
        for (int j = 0; j < 4; j++) {
            int flat = j * 64 + lane;            // 256 chunks of 8 u16
            int row = flat >> 4, c8 = (flat & 15) * 8;
            uint4 v = ((const uint4*)src)[flat];
            *(uint4*)(Smh + row * LDW + c8) = v;
        }
    } else {
        const float* src = (const float*)hidden + (size_t)base * Dd;
#pragma unroll
        for (int j = 0; j < 8; j++) {
            int flat = j * 64 + lane;            // 512 float4 chunks
            int row = flat >> 5, c4 = (flat & 31) * 4;
            float4 v = ((const float4*)src)[flat];
            u16 h0 = f2bf(v.x), h1 = f2bf(v.y), h2 = f2bf(v.z), h3 = f2bf(v.w);
            ushort4 hv; hv.x = h0; hv.y = h1; hv.z = h2; hv.w = h3;
            ushort4 lv; lv.x = f2bf(v.x - bfs(h0)); lv.y = f2bf(v.y - bfs(h1));
                        lv.z = f2bf(v.z - bfs(h2)); lv.w = f2bf(v.w - bfs(h3));
            *(ushort4*)(Smh + row * LDW + c4) = hv;
            *(ushort4*)(Sml + row * LDW + c4) = lv;
        }
    }
    const u16* ph = Smh + m16 * LDW + quad * 8;
    const u16* pl = Sml + m16 * LDW + quad * 8;
    bf16x8 ah[4], al[4];
#pragma unroll
    for (int ks = 0; ks < 4; ks++) {
        ah[ks] = *(const bf16x8*)(ph + ks * 32);
        if (!BF) al[ks] = *(const bf16x8*)(pl + ks * 32);
    }
#pragma unroll
    for (int nt = 0; nt < 8; nt++) {
        int n = nt * 16 + m16;
        f32x4 acc = {0.f, 0.f, 0.f, 0.f};
#pragma unroll
        for (int ks = 0; ks < 4; ks++) {
            bf16x8 bh = *(const bf16x8*)(WsH + n * Dd + ks * 32 + quad * 8);
            acc = __builtin_amdgcn_mfma_f32_16x16x32_bf16(ah[ks], bh, acc, 0, 0, 0);
            if (!BF) {
                bf16x8 bl = *(const bf16x8*)(WsL + n * Dd + ks * 32 + quad * 8);
                acc = __builtin_amdgcn_mfma_f32_16x16x32_bf16(al[ks], bh, acc, 0, 0, 0);
                acc = __builtin_amdgcn_mfma_f32_16x16x32_bf16(ah[ks], bl, acc, 0, 0, 0);
            }
        }
#pragma unroll
        for (int r = 0; r < 4; r++)
            hs[(size_t)(base + quad * 4 + r) * Dd + n] = f2bf(acc[r]);
    }
}
__global__ __launch_bounds__(256, 4) void k_hs(const void* hidden, const u16* WsH,
                                               const u16* WsL, u16* hs, const int* flag) {
    __shared__ __align__(16) u16 SL[4][SLAB];
    u16* slab = SL[threadIdx.x >> 6];
    if (*flag) hs_body<true>(hidden, WsH, WsL, hs, slab);
    else       hs_body<false>(hidden, WsH, WsL, hs, slab);
}

// ---------- counting-sort scatter: slots hold EDGE INDEX ----------
__global__ __launch_bounds__(256) void k_scatter(const int* __restrict__ edges,
                                                 u32* __restrict__ slots,
                                                 int* __restrict__ deg, int nE) {
    int i = blockIdx.x * 256 + threadIdx.x;
    if (i >= nE) return;
    int obj = edges[4*i+3];
    int pos = atomicAdd(&deg[obj], 1);
    if (pos < MAXDEG)
        slots[(size_t)obj * MAXDEG + pos] = (u32)i;
}

// ---------- edge-parallel alpha: 16 lanes per edge, coalesced output ----------
__global__ __launch_bounds__(256) void k_alpha(const int* __restrict__ edges,
                                               const u16* __restrict__ hs,
                                               const float* __restrict__ wrq,
                                               const float* __restrict__ wattnf,
                                               float* __restrict__ alphas, int nE) {
    int tid = blockIdx.x * 256 + threadIdx.x;
    int g = tid >> 4, l = tid & 15;
    if (g >= nE) return;
    int4 ed = ((const int4*)edges)[g];          // bat, sub, rel, obj
    const u16*   hp = hs  + (size_t)ed.y * Dd + l * 8;
    const float* wp = wrq + (size_t)(ed.x * Rr + ed.z) * Dd + l * 8;
    uint4  hv = *(const uint4*)hp;
    float4 w0 = *(const float4*)wp;
    float4 w1 = *(const float4*)(wp + 4);
    float4 a0 = *(const float4*)(wattnf + l * 8);
    float4 a1 = *(const float4*)(wattnf + l * 8 + 4);
    float p = fmaxf(bflo(hv.x) + w0.x, 0.f) * a0.x + fmaxf(bfhi(hv.x) + w0.y, 0.f) * a0.y
            + fmaxf(bflo(hv.y) + w0.z, 0.f) * a0.z + fmaxf(bfhi(hv.y) + w0.w, 0.f) * a0.w
            + fmaxf(bflo(hv.z) + w1.x, 0.f) * a1.x + fmaxf(bfhi(hv.z) + w1.y, 0.f) * a1.y
            + fmaxf(bflo(hv.w) + w1.z, 0.f) * a1.z + fmaxf(bfhi(hv.w) + w1.w, 0.f) * a1.w;
#pragma unroll
    for (int m = 8; m >= 1; m >>= 1) p += __shfl_xor(p, m, 16);
    if (l == 0)
        alphas[g] = 1.f / (1.f + __expf(-p));
}

// ---------- fused: light gather (idx->alpha,hidden,rela) -> slab -> 2-layer MFMA MLP ----------
// MODE: 0 = full (real), 1 = gather-only, 2 = mlp-only, 4 = gather with L1-hot operands
template<bool BF, int MODE>
__device__ __forceinline__ void edge_body(u32 idx, int lane, int base,
                                          const int4* __restrict__ edges4,
                                          const float* __restrict__ alphas,
                                          const void* __restrict__ hidden,
                                          const float* __restrict__ relaf,
                                          float& a0, float& a1) {
    int sub, rel;
    float al;
    if (MODE == 4) {
        // pinned-uniform, L1-hot after first touch; keeps loop/arith structure
        sub = base; rel = 0; al = 1.0f;
        (void)edges4; (void)alphas; (void)idx;
    } else {
        int4 ed = edges4[idx];
        al = alphas[idx];
        sub = ed.y; rel = ed.z;
    }
    float mh0, mh1;
    if (BF) { u32 mh = ((const u32*)hidden)[(size_t)sub * 64 + lane]; mh0 = bflo(mh); mh1 = bfhi(mh); }
    else    { float2 mh = ((const float2*)hidden)[(size_t)sub * 64 + lane]; mh0 = mh.x; mh1 = mh.y; }
    float2 mr = ((const float2*)relaf)[rel * 64 + lane];
    a0 += mh0 * mr.x * al;
    a1 += mh1 * mr.y * al;
}

template<bool BF, int MODE>
__device__ void fused_body(const u32* __restrict__ slots, const int* __restrict__ deg,
                           const int4* __restrict__ edges4, const float* __restrict__ alphas,
                           const void* __restrict__ hidden, const float* __restrict__ relaf,
                           const u16* w1H, const u16* w1L, const u16* w2H, const u16* w2L,
                           const float* b1f, const float* b2f, void* out,
                           u16* __restrict__ Smh) {
    int t = threadIdx.x, w = t >> 6, lane = t & 63;
    int m16 = lane & 15, quad = lane >> 4;
    int base = blockIdx.x * 64 + w * 16;
    u16* Sml = Smh + 16 * LDW;

    // ---- gather phase (skipped in MODE 2) ----
    if (MODE != 2) {
        for (int i = 0; i < 16; i += 2) {
            int nA = base + i, nB = base + i + 1;
            int dA = deg[nA]; if (dA > MAXDEG) dA = MAXDEG;
            int dB = deg[nB]; if (dB > MAXDEG) dB = MAXDEG;
            const u32* sA = slots + (size_t)nA * MAXDEG;
            const u32* sB = slots + (size_t)nB * MAXDEG;
            float aA0 = 0.f, aA1 = 0.f, cA0 = 0.f, cA1 = 0.f;
            float aB0 = 0.f, aB1 = 0.f, cB0 = 0.f, cB1 = 0.f;
            int eA = 0, eB = 0;

            while (eA + 1 < dA && eB + 1 < dB) {
                u32 iA0 = sA[eA], iA1 = sA[eA + 1];
                u32 iB0 = sB[eB], iB1 = sB[eB + 1];
                edge_body<BF, MODE>(iA0, lane, base, edges4, alphas, hidden, relaf, aA0, aA1);
                edge_body<BF, MODE>(iB0, lane, base, edges4, alphas, hidden, relaf, aB0, aB1);
                edge_body<BF, MODE>(iA1, lane, base, edges4, alphas, hidden, relaf, cA0, cA1);
                edge_body<BF, MODE>(iB1, lane, base, edges4, alphas, hidden, relaf, cB0, cB1);
                eA += 2; eB += 2;
            }
            while (eA < dA && eB < dB) {
                u32 iA0 = sA[eA], iB0 = sB[eB];
                edge_body<BF, MODE>(iA0, lane, base, edges4, alphas, hidden, relaf, aA0, aA1);
                edge_body<BF, MODE>(iB0, lane, base, edges4, alphas, hidden, relaf, aB0, aB1);
                eA++; eB++;
            }
            while (eA + 1 < dA) {
                u32 i0 = sA[eA], i1 = sA[eA + 1];
                edge_body<BF, MODE>(i0, lane, base, edges4, alphas, hidden, relaf, aA0, aA1);
                edge_body<BF, MODE>(i1, lane, base, edges4, alphas, hidden, relaf, cA0, cA1);
                eA += 2;
            }
            if (eA < dA)
                edge_body<BF, MODE>(sA[eA], lane, base, edges4, alphas, hidden, relaf, aA0, aA1);
            while (eB + 1 < dB) {
                u32 i0 = sB[eB], i1 = sB[eB + 1];
                edge_body<BF, MODE>(i0, lane, base, edges4, alphas, hidden, relaf, aB0, aB1);
                edge_body<BF, MODE>(i1, lane, base, edges4, alphas, hidden, relaf, cB0, cB1);
                eB += 2;
            }
            if (eB < dB)
                edge_body<BF, MODE>(sB[eB], lane, base, edges4, alphas, hidden, relaf, aB0, aB1);

            aA0 += cA0; aA1 += cA1;
            aB0 += cB0; aB1 += cB1;
            u16 hA0 = f2bf(aA0), lA0 = f2bf(aA0 - bfs(hA0));
            u16 hA1 = f2bf(aA1), lA1 = f2bf(aA1 - bfs(hA1));
            *(u32*)(Smh + i * LDW + 2 * lane) = (u32)hA0 | ((u32)hA1 << 16);
            *(u32*)(Sml + i * LDW + 2 * lane) = (u32)lA0 | ((u32)lA1 << 16);
            u16 hB0 = f2bf(aB0), lB0 = f2bf(aB0 - bfs(hB0));
            u16 hB1 = f2bf(aB1), lB1 = f2bf(aB1 - bfs(hB1));
            *(u32*)(Smh + (i + 1) * LDW + 2 * lane) = (u32)hB0 | ((u32)hB1 << 16);
            *(u32*)(Sml + (i + 1) * LDW + 2 * lane) = (u32)lB0 | ((u32)lB1 << 16);
        }
    }

    // MODE 1 / MODE 4: flush slab to out (keeps gather live), skip MLP
    if (MODE == 1 || MODE == 4) {
#pragma unroll
        for (int r = 0; r < 16; r++) {
            u32 hv = *(u32*)(Smh + r * LDW + 2 * lane);
            u32 lv = *(u32*)(Sml + r * LDW + 2 * lane);
            ((u32*)out)[(size_t)(base + r) * 64 + lane] = hv ^ lv;
        }
        return;
    }

    // ---- layer 1: mid = agg @ W1^T + b1 ----
    const u16* ph = Smh + m16 * LDW + quad * 8;
    const u16* pl = Sml + m16 * LDW + quad * 8;
    bf16x8 ah[4], al[4];
#pragma unroll
    for (int ks = 0; ks < 4; ks++) {
        ah[ks] = *(const bf16x8*)(ph + ks * 32);
        al[ks] = *(const bf16x8*)(pl + ks * 32);
    }
#pragma unroll
    for (int nt = 0; nt < 8; nt++) {
        int n = nt * 16 + m16;
        f32x4 acc = {0.f, 0.f, 0.f, 0.f};
#pragma unroll
        for (int ks = 0; ks < 4; ks++) {
            bf16x8 bh = *(const bf16x8*)(w1H + n * Dd + ks * 32 + quad * 8);
            acc = __builtin_amdgcn_mfma_f32_16x16x32_bf16(ah[ks], bh, acc, 0, 0, 0);
            acc = __builtin_amdgcn_mfma_f32_16x16x32_bf16(al[ks], bh, acc, 0, 0, 0);
            if (!BF) {
                bf16x8 bl = *(const bf16x8*)(w1L + n * Dd + ks * 32 + quad * 8);
                acc = __builtin_amdgcn_mfma_f32_16x16x32_bf16(ah[ks], bl, acc, 0, 0, 0);
            }
        }
        float bv = b1f[n];
#pragma unroll
        for (int r = 0; r < 4; r++) {
            float v = acc[r] + bv;
            int row = quad * 4 + r;
            u16 h = f2bf(v);
            Smh[row * LDW + n] = h;
            Sml[row * LDW + n] = f2bf(v - bfs(h));
        }
    }

    // ---- layer 2: out = relu(mid @ W2^T + b2), masked by deg ----
    bf16x8 mh[4], ml[4];
#pragma unroll
    for (int ks = 0; ks < 4; ks++) {
        mh[ks] = *(const bf16x8*)(ph + ks * 32);
        ml[ks] = *(const bf16x8*)(pl + ks * 32);
    }
    int dg[4];
#pragma unroll
    for (int r = 0; r < 4; r++) dg[r] = deg[base + quad * 4 + r];
#pragma unroll
    for (int nt = 0; nt < 8; nt++) {
        int n = nt * 16 + m16;
        f32x4 acc = {0.f, 0.f, 0.f, 0.f};
#pragma unroll
        for (int ks = 0; ks < 4; ks++) {
            bf16x8 bh = *(const bf16x8*)(w2H + n * Dd + ks * 32 + quad * 8);
            acc = __builtin_amdgcn_mfma_f32_16x16x32_bf16(mh[ks], bh, acc, 0, 0, 0);
            acc = __builtin_amdgcn_mfma_f32_16x16x32_bf16(ml[ks], bh, acc, 0, 0, 0);
            if (!BF) {
                bf16x8 bl = *(const bf16x8*)(w2L + n * Dd + ks * 32 + quad * 8);
                acc = __builtin_amdgcn_mfma_f32_16x16x32_bf16(mh[ks], bl, acc, 0, 0, 0);
            }
        }
        float bv = b2f[n];
#pragma unroll
        for (int r = 0; r < 4; r++) {
            float v = fmaxf(acc[r] + bv, 0.f);
            if (dg[r] == 0) v = 0.f;
            size_t o = (size_t)(base + quad * 4 + r) * Dd + n;
            if (BF) ((u16*)out)[o] = f2bf(v);
            else    ((float*)out)[o] = v;
        }
    }
}

#define FUSED_WRAP(NAME, MODE)                                                              \
__global__ __launch_bounds__(256, 4) void NAME(const u32* slots, const int* deg,            \
                                               const int4* edges4, const float* alphas,     \
                                               const void* hidden, const float* relaf,      \
                                               const u16* w1H, const u16* w1L,              \
                                               const u16* w2H, const u16* w2L,              \
                                               const float* b1f, const float* b2f,          \
                                               void* out, const int* flag) {                \
    __shared__ __align__(16) u16 SL[4][SLAB];                                               \
    u16* slab = SL[threadIdx.x >> 6];                                                       \
    if (*flag) fused_body<true, MODE>(slots, deg, edges4, alphas, hidden, relaf,            \
                                      w1H, w1L, w2H, w2L, b1f, b2f, out, slab);             \
    else       fused_body<false, MODE>(slots, deg, edges4, alphas, hidden, relaf,           \
                                       w1H, w1L, w2H, w2L, b1f, b2f, out, slab);            \
}

FUSED_WRAP(k_fused, 0)
FUSED_WRAP(k_abl_gather, 1)
FUSED_WRAP(k_abl_mlp, 2)
FUSED_WRAP(k_abl_hot, 4)

extern "C" void kernel_launch(void* const* d_in, const int* in_sizes, int n_in,
                              void* d_out, int out_size, void* d_ws, size_t ws_size,
                              hipStream_t stream) {
    const void* query  = d_in[0];
    const void* hidden = d_in[3];
    const int*  edges  = (const int*)d_in[4];
    const void* Ws     = d_in[6];
    const void* Wr     = d_in[7];
    const void* Wqr    = d_in[8];
    const void* Wqrb   = d_in[9];
    const void* Wattn  = d_in[10];
    const void* rela   = d_in[11];
    const void* w1     = d_in[12];
    const void* b1     = d_in[13];
    const void* w2     = d_in[14];
    const void* b2     = d_in[15];

    char* ws = (char*)d_ws;
    u16*   hs     = (u16*)ws;                        //  51,200,000 B
    float* wrq    = (float*)(ws +  51200000);        //     409,600 B
    u32*   slots  = (u32*) (ws +  51609600);         //  25,600,000 B (edge indices)
    int*   deg    = (int*) (ws +  77209600);         //     800,000 B
    u16*   WsH    = (u16*) (ws +  78009600);
    u16*   WsL    = (u16*) (ws +  78042368);
    u16*   w1H    = (u16*) (ws +  78075136);
    u16*   w1L    = (u16*) (ws +  78107904);
    u16*   w2H    = (u16*) (ws +  78140672);
    u16*   w2L    = (u16*) (ws +  78173440);
    float* b1f    = (float*)(ws +  78206208);
    float* b2f    = (float*)(ws +  78206720);
    float* wattnf = (float*)(ws +  78207232);
    float* relaf  = (float*)(ws +  78207744);        //     102,400 B
    int*   flag   = (int*) (ws +  78310144);
    float* alphas = (float*)(ws +  78310400);        //   2,400,000 B (per-edge alpha)

    int nE = in_sizes[4] / 4;

    k_probe<<<1, 64, 0, stream>>>((const u32*)query, flag);
    hipMemsetAsync(deg, 0, (size_t)BN * 4, stream);
    k_wprep<<<294, 256, 0, stream>>>(Ws, w1, w2, b1, b2, Wattn, rela,
                                     WsH, WsL, w1H, w1L, w2H, w2L,
                                     b1f, b2f, wattnf, relaf, flag);
    k_wrq<<<Bb * Rr, 128, 0, stream>>>(Wr, Wqr, Wqrb, rela, query, wrq, flag);
    k_hs<<<BN / 64, 256, 0, stream>>>(hidden, WsH, WsL, hs, flag);
    k_scatter<<<(nE + 255) / 256, 256, 0, stream>>>(edges, slots, deg, nE);
    {
        long long thr = (long long)nE * 16;
        int blocks = (int)((thr + 255) / 256);
        k_alpha<<<blocks, 256, 0, stream>>>(edges, hs, wrq, wattnf, alphas, nE);
    }
    // ---- ablation dispatches (diagnostic; write garbage to d_out, overwritten below) ----
    k_abl_gather<<<BN / 64, 256, 0, stream>>>(slots, deg, (const int4*)edges, alphas,
                                              hidden, relaf,
                                              w1H, w1L, w2H, w2L, b1f, b2f, d_out, flag);
    k_abl_mlp<<<BN / 64, 256, 0, stream>>>(slots, deg, (const int4*)edges, alphas,
                                           hidden, relaf,
                                           w1H, w1L, w2H, w2L, b1f, b2f, d_out, flag);
    k_abl_hot<<<BN / 64, 256, 0, stream>>>(slots, deg, (const int4*)edges, alphas,
                                           hidden, relaf,
                                           w1H, w1L, w2H, w2L, b1f, b2f, d_out, flag);
    // ---- real k_fused last: overwrites every output element ----
    k_fused<<<BN / 64, 256, 0, stream>>>(slots, deg, (const int4*)edges, alphas,
                                         hidden, relaf,
                                         w1H, w1L, w2H, w2L, b1f, b2f, d_out, flag);
}

// Round 7
// 665.138 us; speedup vs baseline: 1.5468x; 1.5468x over previous
//
#include <hip/hip_runtime.h>

typedef unsigned int u32;
typedef unsigned short u16;
typedef unsigned long long u64;
typedef __attribute__((ext_vector_type(8))) short bf16x8;
typedef __attribute__((ext_vector_type(4))) float f32x4;

#define Bb 4
#define Nn 50000
#define Dd 128
#define Rr 200
#define BN (Bb*Nn)
#define MAXDEG 16
#define LDW 136          // u16 row stride inside a wave slab (272 B, 16B-aligned)
#define SLAB 4352        // u16 per wave slab: 2 tiles x 16 rows x 136

// ---------- scalar helpers ----------
__device__ __forceinline__ float bfs(u16 u) { return __uint_as_float(((u32)u) << 16); }
__device__ __forceinline__ float bflo(u32 u) { return __uint_as_float(u << 16); }
__device__ __forceinline__ float bfhi(u32 u) { return __uint_as_float(u & 0xffff0000u); }
__device__ __forceinline__ u16 f2bf(float f) {
    u32 x = __float_as_uint(f);
    return (u16)((x + 0x7fffu + ((x >> 16) & 1u)) >> 16);
}
template<bool BF>
__device__ __forceinline__ float ld1(const void* p, int i) {
    if (BF) return bfs(((const u16*)p)[i]);
    else    return ((const float*)p)[i];
}

// ---------- dtype probe: bf16-packed vs f32 ----------
__global__ void k_probe(const u32* __restrict__ q, int* __restrict__ flag) {
    int t = threadIdx.x;
    u32 w = q[t];
    int e = (int)((w >> 7) & 0xffu);
    bool plaus = (e >= 100 && e <= 150);
    unsigned long long m = __ballot(plaus);
    if (t == 0) flag[0] = (__popcll(m) >= 56) ? 1 : 0;
}

// ---------- prep: split weights to bf16 hi/lo, f32 copies of small tensors ----------
__global__ __launch_bounds__(256) void k_wprep(
    const void* Ws, const void* w1, const void* w2,
    const void* b1, const void* b2, const void* wattn, const void* rela,
    u16* WsH, u16* WsL, u16* w1H, u16* w1L, u16* w2H, u16* w2L,
    float* b1f, float* b2f, float* wattnf, float* relaf, const int* flag) {
    bool bf = (*flag != 0);
    int i = blockIdx.x * 256 + threadIdx.x;
    if (i < 16384) {
        float x = bf ? bfs(((const u16*)Ws)[i]) : ((const float*)Ws)[i];
        u16 h = f2bf(x); WsH[i] = h; WsL[i] = f2bf(x - bfs(h));
    } else if (i < 32768) {
        int j = i - 16384;
        float x = bf ? bfs(((const u16*)w1)[j]) : ((const float*)w1)[j];
        u16 h = f2bf(x); w1H[j] = h; w1L[j] = f2bf(x - bfs(h));
    } else if (i < 49152) {
        int j = i - 32768;
        float x = bf ? bfs(((const u16*)w2)[j]) : ((const float*)w2)[j];
        u16 h = f2bf(x); w2H[j] = h; w2L[j] = f2bf(x - bfs(h));
    } else if (i < 49152 + 128) {
        int j = i - 49152;
        b1f[j] = bf ? bfs(((const u16*)b1)[j]) : ((const float*)b1)[j];
    } else if (i < 49152 + 256) {
        int j = i - 49152 - 128;
        b2f[j] = bf ? bfs(((const u16*)b2)[j]) : ((const float*)b2)[j];
    } else if (i < 49152 + 384) {
        int j = i - 49152 - 256;
        wattnf[j] = bf ? bfs(((const u16*)wattn)[j]) : ((const float*)wattn)[j];
    } else if (i < 49152 + 384 + 25600) {
        int j = i - 49152 - 384;
        relaf[j] = bf ? bfs(((const u16*)rela)[j]) : ((const float*)rela)[j];
    }
}

// ---------- wrq[b*R+r][a] = Wr.rela_r + Wqr.query_b + bias (tiny, f32 VALU) ----------
template<bool BF>
__device__ __forceinline__ float dotrow1(const void* W, int row, const float* s) {
    float acc = 0.f;
    if (BF) {
        const uint4* wv = (const uint4*)((const u16*)W + row * Dd);
#pragma unroll
        for (int k = 0; k < 16; k++) {
            uint4 u = wv[k];
            acc += bflo(u.x)*s[k*8+0] + bfhi(u.x)*s[k*8+1]
                 + bflo(u.y)*s[k*8+2] + bfhi(u.y)*s[k*8+3]
                 + bflo(u.z)*s[k*8+4] + bfhi(u.z)*s[k*8+5]
                 + bflo(u.w)*s[k*8+6] + bfhi(u.w)*s[k*8+7];
        }
    } else {
        const float4* wv = (const float4*)((const float*)W + row * Dd);
#pragma unroll
        for (int k = 0; k < 32; k++) {
            float4 u = wv[k];
            acc += u.x*s[4*k] + u.y*s[4*k+1] + u.z*s[4*k+2] + u.w*s[4*k+3];
        }
    }
    return acc;
}
template<bool BF>
__device__ void k_wrq_body(const void* Wr, const void* Wqr, const void* bias,
                           const void* rela, const void* query, float* wrq, float* s) {
    int br = blockIdx.x;
    int b = br / Rr, r = br % Rr;
    int a = threadIdx.x;
    s[a]      = ld1<BF>(rela,  r * Dd + a);
    s[Dd + a] = ld1<BF>(query, b * Dd + a);
    __syncthreads();
    wrq[br * Dd + a] = ld1<BF>(bias, a) + dotrow1<BF>(Wr, a, s) + dotrow1<BF>(Wqr, a, s + Dd);
}
__global__ __launch_bounds__(128) void k_wrq(const void* Wr, const void* Wqr, const void* bias,
                                             const void* rela, const void* query, float* wrq,
                                             const int* flag) {
    __shared__ float s[2 * Dd];
    if (*flag) k_wrq_body<true>(Wr, Wqr, bias, rela, query, wrq, s);
    else       k_wrq_body<false>(Wr, Wqr, bias, rela, query, wrq, s);
}

// ---------- hs = hidden @ Ws^T via split-bf16 MFMA (wave-private slab, no barriers) ----------
template<bool BF>
__device__ void hs_body(const void* hidden, const u16* WsH, const u16* WsL, u16* hs,
                        u16* __restrict__ Smh) {
    int t = threadIdx.x, lane = t & 63;
    int m16 = lane & 15, quad = lane >> 4;
    int w = t >> 6;
    int base = blockIdx.x * 64 + w * 16;
    u16* Sml = Smh + 16 * LDW;

    if (BF) {
        const u16* src = (const u16*)hidden + (size_t)base * Dd;
#pragma unroll
        for (int j = 0; j < 4; j++) {
            int flat = j * 64 + lane;            // 256 chunks of 8 u16
            int row = flat >> 4, c8 = (flat & 15) * 8;
            uint4 v = ((const uint4*)src)[flat];
            *(uint4*)(Smh + row * LDW + c8) = v;
        }
    } else {
        const float* src = (const float*)hidden + (size_t)base * Dd;
#pragma unroll
        for (int j = 0; j < 8; j++) {
            int flat = j * 64 + lane;            // 512 float4 chunks
            int row = flat >> 5, c4 = (flat & 31) * 4;
            float4 v = ((const float4*)src)[flat];
            u16 h0 = f2bf(v.x), h1 = f2bf(v.y), h2 = f2bf(v.z), h3 = f2bf(v.w);
            ushort4 hv; hv.x = h0; hv.y = h1; hv.z = h2; hv.w = h3;
            ushort4 lv; lv.x = f2bf(v.x - bfs(h0)); lv.y = f2bf(v.y - bfs(h1));
                        lv.z = f2bf(v.z - bfs(h2)); lv.w = f2bf(v.w - bfs(h3));
            *(ushort4*)(Smh + row * LDW + c4) = hv;
            *(ushort4*)(Sml + row * LDW + c4) = lv;
        }
    }
    const u16* ph = Smh + m16 * LDW + quad * 8;
    const u16* pl = Sml + m16 * LDW + quad * 8;
    bf16x8 ah[4], al[4];
#pragma unroll
    for (int ks = 0; ks < 4; ks++) {
        ah[ks] = *(const bf16x8*)(ph + ks * 32);
        if (!BF) al[ks] = *(const bf16x8*)(pl + ks * 32);
    }
#pragma unroll
    for (int nt = 0; nt < 8; nt++) {
        int n = nt * 16 + m16;
        f32x4 acc = {0.f, 0.f, 0.f, 0.f};
#pragma unroll
        for (int ks = 0; ks < 4; ks++) {
            bf16x8 bh = *(const bf16x8*)(WsH + n * Dd + ks * 32 + quad * 8);
            acc = __builtin_amdgcn_mfma_f32_16x16x32_bf16(ah[ks], bh, acc, 0, 0, 0);
            if (!BF) {
                bf16x8 bl = *(const bf16x8*)(WsL + n * Dd + ks * 32 + quad * 8);
                acc = __builtin_amdgcn_mfma_f32_16x16x32_bf16(al[ks], bh, acc, 0, 0, 0);
                acc = __builtin_amdgcn_mfma_f32_16x16x32_bf16(ah[ks], bl, acc, 0, 0, 0);
            }
        }
#pragma unroll
        for (int r = 0; r < 4; r++)
            hs[(size_t)(base + quad * 4 + r) * Dd + n] = f2bf(acc[r]);
    }
}
__global__ __launch_bounds__(256, 4) void k_hs(const void* hidden, const u16* WsH,
                                               const u16* WsL, u16* hs, const int* flag) {
    __shared__ __align__(16) u16 SL[4][SLAB];
    u16* slab = SL[threadIdx.x >> 6];
    if (*flag) hs_body<true>(hidden, WsH, WsL, hs, slab);
    else       hs_body<false>(hidden, WsH, WsL, hs, slab);
}

// ---------- fused scatter+alpha: 16 lanes per edge; writes u64 (rec | alpha) slot ----------
__global__ __launch_bounds__(256) void k_alpha(const int* __restrict__ edges,
                                               const u16* __restrict__ hs,
                                               const float* __restrict__ wrq,
                                               const float* __restrict__ wattnf,
                                               u64* __restrict__ slotsAL,
                                               int* __restrict__ deg, int nE) {
    int tid = blockIdx.x * 256 + threadIdx.x;
    int g = tid >> 4, l = tid & 15;
    if (g >= nE) return;
    int4 ed = ((const int4*)edges)[g];          // bat, sub, rel, obj
    const u16*   hp = hs  + (size_t)ed.y * Dd + l * 8;
    const float* wp = wrq + (size_t)(ed.x * Rr + ed.z) * Dd + l * 8;
    uint4  hv = *(const uint4*)hp;
    float4 w0 = *(const float4*)wp;
    float4 w1 = *(const float4*)(wp + 4);
    float4 a0 = *(const float4*)(wattnf + l * 8);
    float4 a1 = *(const float4*)(wattnf + l * 8 + 4);
    float p = fmaxf(bflo(hv.x) + w0.x, 0.f) * a0.x + fmaxf(bfhi(hv.x) + w0.y, 0.f) * a0.y
            + fmaxf(bflo(hv.y) + w0.z, 0.f) * a0.z + fmaxf(bfhi(hv.y) + w0.w, 0.f) * a0.w
            + fmaxf(bflo(hv.z) + w1.x, 0.f) * a1.x + fmaxf(bfhi(hv.z) + w1.y, 0.f) * a1.y
            + fmaxf(bflo(hv.w) + w1.z, 0.f) * a1.z + fmaxf(bfhi(hv.w) + w1.w, 0.f) * a1.w;
#pragma unroll
    for (int m = 8; m >= 1; m >>= 1) p += __shfl_xor(p, m, 16);
    if (l == 0) {
        float alpha = 1.f / (1.f + __expf(-p));
        int pos = atomicAdd(&deg[ed.w], 1);
        if (pos < MAXDEG) {
            u32 rec = (u32)ed.y | ((u32)ed.z << 18);
            slotsAL[(size_t)ed.w * MAXDEG + pos] =
                (u64)rec | ((u64)__float_as_uint(alpha) << 32);
        }
    }
}

// ---------- fused: zero-hop gather (LDS-staged slots) -> slab -> 2-layer MFMA MLP ----------
template<bool BF>
__device__ __forceinline__ void gfma(u32 rec, float al, int lane,
                                     const void* __restrict__ hidden,
                                     const float* __restrict__ relaf,
                                     float& a0, float& a1) {
    int sub = rec & 0x3FFFF, rel = (rec >> 18) & 0xFF;
    float mh0, mh1;
    if (BF) { u32 mh = ((const u32*)hidden)[(size_t)sub * 64 + lane]; mh0 = bflo(mh); mh1 = bfhi(mh); }
    else    { float2 mh = ((const float2*)hidden)[(size_t)sub * 64 + lane]; mh0 = mh.x; mh1 = mh.y; }
    float2 mr = ((const float2*)relaf)[rel * 64 + lane];
    a0 += mh0 * mr.x * al;
    a1 += mh1 * mr.y * al;
}

template<bool BF>
__device__ void fused_body(const u64* __restrict__ slotsAL, const int* __restrict__ deg,
                           const void* __restrict__ hidden, const float* __restrict__ relaf,
                           const u16* w1H, const u16* w1L, const u16* w2H, const u16* w2L,
                           const float* b1f, const float* b2f, void* out,
                           u16* __restrict__ Smh, char* __restrict__ SB) {
    int t = threadIdx.x, lane = t & 63;
    int m16 = lane & 15, quad = lane >> 4;
    int w = t >> 6;
    int base = blockIdx.x * 64 + w * 16;
    u16* Sml = Smh + 16 * LDW;

    // ---- stage all 16 nodes' first-8 (rec|alpha) slots into LDS: one dwordx4/lane ----
    // lane covers node (lane>>2), 16B chunk (lane&3); node row = MAXDEG*8 = 128B, take first 64B
    {
        const uint4* sp = (const uint4*)((const char*)(slotsAL + (size_t)base * MAXDEG)
                                         + (size_t)(lane >> 2) * (MAXDEG * 8) + (lane & 3) * 16);
        *(uint4*)(SB + lane * 16) = *sp;     // SB byte: node*64 + e*8 -> (rec, alpha-bits)
    }
    // same-wave RAW on LDS; compiler inserts lgkmcnt before first ds_read

    // ---- gather phase: node pairs, masked 4-wide groups, zero dependent hops ----
    for (int i = 0; i < 16; i += 2) {
        int nA = base + i, nB = nA + 1;
        int dA = deg[nA]; if (dA > MAXDEG) dA = MAXDEG;
        int dB = deg[nB]; if (dB > MAXDEG) dB = MAXDEG;
        const char* pA = SB + i * 64;
        const char* pB = pA + 64;
        float aA0 = 0.f, aA1 = 0.f, aB0 = 0.f, aB1 = 0.f;

        // group 1: edges 0..3 of both nodes (8 independent payload gathers)
#pragma unroll
        for (int e = 0; e < 4; e++) {
            uint2 qA = *(const uint2*)(pA + e * 8);
            uint2 qB = *(const uint2*)(pB + e * 8);
            u32  rA = (e < dA) ? qA.x : 0u;
            float lA = (e < dA) ? __uint_as_float(qA.y) : 0.f;
            u32  rB = (e < dB) ? qB.x : 0u;
            float lB = (e < dB) ? __uint_as_float(qB.y) : 0.f;
            gfma<BF>(rA, lA, lane, hidden, relaf, aA0, aA1);
            gfma<BF>(rB, lB, lane, hidden, relaf, aB0, aB1);
        }
        // group 2: edges 4..7 (skipped for ~82% of pairs; wave-uniform branch)
        if (dA > 4 || dB > 4) {
#pragma unroll
            for (int e = 4; e < 8; e++) {
                uint2 qA = *(const uint2*)(pA + e * 8);
                uint2 qB = *(const uint2*)(pB + e * 8);
                u32  rA = (e < dA) ? qA.x : 0u;
                float lA = (e < dA) ? __uint_as_float(qA.y) : 0.f;
                u32  rB = (e < dB) ? qB.x : 0u;
                float lB = (e < dB) ? __uint_as_float(qB.y) : 0.f;
                gfma<BF>(rA, lA, lane, hidden, relaf, aA0, aA1);
                gfma<BF>(rB, lB, lane, hidden, relaf, aB0, aB1);
            }
        }
        // rare tails (deg > 8) straight from global
        for (int e = 8; e < dA; e++) {
            u64 q = slotsAL[(size_t)nA * MAXDEG + e];
            gfma<BF>((u32)q, __uint_as_float((u32)(q >> 32)), lane, hidden, relaf, aA0, aA1);
        }
        for (int e = 8; e < dB; e++) {
            u64 q = slotsAL[(size_t)nB * MAXDEG + e];
            gfma<BF>((u32)q, __uint_as_float((u32)(q >> 32)), lane, hidden, relaf, aB0, aB1);
        }

        u16 hA0 = f2bf(aA0), lA0 = f2bf(aA0 - bfs(hA0));
        u16 hA1 = f2bf(aA1), lA1 = f2bf(aA1 - bfs(hA1));
        *(u32*)(Smh + i * LDW + 2 * lane) = (u32)hA0 | ((u32)hA1 << 16);
        *(u32*)(Sml + i * LDW + 2 * lane) = (u32)lA0 | ((u32)lA1 << 16);
        u16 hB0 = f2bf(aB0), lB0 = f2bf(aB0 - bfs(hB0));
        u16 hB1 = f2bf(aB1), lB1 = f2bf(aB1 - bfs(hB1));
        *(u32*)(Smh + (i + 1) * LDW + 2 * lane) = (u32)hB0 | ((u32)hB1 << 16);
        *(u32*)(Sml + (i + 1) * LDW + 2 * lane) = (u32)lB0 | ((u32)lB1 << 16);
    }

    // ---- layer 1: mid = agg @ W1^T + b1 (A-frags in regs, mid back to slab) ----
    const u16* ph = Smh + m16 * LDW + quad * 8;
    const u16* pl = Sml + m16 * LDW + quad * 8;
    bf16x8 ah[4], al[4];
#pragma unroll
    for (int ks = 0; ks < 4; ks++) {
        ah[ks] = *(const bf16x8*)(ph + ks * 32);
        al[ks] = *(const bf16x8*)(pl + ks * 32);
    }
#pragma unroll
    for (int nt = 0; nt < 8; nt++) {
        int n = nt * 16 + m16;
        f32x4 acc = {0.f, 0.f, 0.f, 0.f};
#pragma unroll
        for (int ks = 0; ks < 4; ks++) {
            bf16x8 bh = *(const bf16x8*)(w1H + n * Dd + ks * 32 + quad * 8);
            acc = __builtin_amdgcn_mfma_f32_16x16x32_bf16(ah[ks], bh, acc, 0, 0, 0);
            acc = __builtin_amdgcn_mfma_f32_16x16x32_bf16(al[ks], bh, acc, 0, 0, 0);
            if (!BF) {
                bf16x8 bl = *(const bf16x8*)(w1L + n * Dd + ks * 32 + quad * 8);
                acc = __builtin_amdgcn_mfma_f32_16x16x32_bf16(ah[ks], bl, acc, 0, 0, 0);
            }
        }
        float bv = b1f[n];
#pragma unroll
        for (int r = 0; r < 4; r++) {
            float v = acc[r] + bv;
            int row = quad * 4 + r;
            u16 h = f2bf(v);
            Smh[row * LDW + n] = h;
            Sml[row * LDW + n] = f2bf(v - bfs(h));
        }
    }

    // ---- layer 2: out = relu(mid @ W2^T + b2), masked by deg ----
    bf16x8 mh[4], ml[4];
#pragma unroll
    for (int ks = 0; ks < 4; ks++) {
        mh[ks] = *(const bf16x8*)(ph + ks * 32);
        ml[ks] = *(const bf16x8*)(pl + ks * 32);
    }
    int dg[4];
#pragma unroll
    for (int r = 0; r < 4; r++) dg[r] = deg[base + quad * 4 + r];
#pragma unroll
    for (int nt = 0; nt < 8; nt++) {
        int n = nt * 16 + m16;
        f32x4 acc = {0.f, 0.f, 0.f, 0.f};
#pragma unroll
        for (int ks = 0; ks < 4; ks++) {
            bf16x8 bh = *(const bf16x8*)(w2H + n * Dd + ks * 32 + quad * 8);
            acc = __builtin_amdgcn_mfma_f32_16x16x32_bf16(mh[ks], bh, acc, 0, 0, 0);
            acc = __builtin_amdgcn_mfma_f32_16x16x32_bf16(ml[ks], bh, acc, 0, 0, 0);
            if (!BF) {
                bf16x8 bl = *(const bf16x8*)(w2L + n * Dd + ks * 32 + quad * 8);
                acc = __builtin_amdgcn_mfma_f32_16x16x32_bf16(mh[ks], bl, acc, 0, 0, 0);
            }
        }
        float bv = b2f[n];
#pragma unroll
        for (int r = 0; r < 4; r++) {
            float v = fmaxf(acc[r] + bv, 0.f);
            if (dg[r] == 0) v = 0.f;
            size_t o = (size_t)(base + quad * 4 + r) * Dd + n;
            if (BF) ((u16*)out)[o] = f2bf(v);
            else    ((float*)out)[o] = v;
        }
    }
}
__global__ __launch_bounds__(256, 4) void k_fused(const u64* slotsAL, const int* deg,
                                                  const void* hidden, const float* relaf,
                                                  const u16* w1H, const u16* w1L,
                                                  const u16* w2H, const u16* w2L,
                                                  const float* b1f, const float* b2f,
                                                  void* out, const int* flag) {
    __shared__ __align__(16) u16 SL[4][SLAB];
    __shared__ __align__(16) char SBL[4][1024];
    int w = threadIdx.x >> 6;
    if (*flag) fused_body<true>(slotsAL, deg, hidden, relaf,
                                w1H, w1L, w2H, w2L, b1f, b2f, out, SL[w], SBL[w]);
    else       fused_body<false>(slotsAL, deg, hidden, relaf,
                                 w1H, w1L, w2H, w2L, b1f, b2f, out, SL[w], SBL[w]);
}

extern "C" void kernel_launch(void* const* d_in, const int* in_sizes, int n_in,
                              void* d_out, int out_size, void* d_ws, size_t ws_size,
                              hipStream_t stream) {
    const void* query  = d_in[0];
    const void* hidden = d_in[3];
    const int*  edges  = (const int*)d_in[4];
    const void* Ws     = d_in[6];
    const void* Wr     = d_in[7];
    const void* Wqr    = d_in[8];
    const void* Wqrb   = d_in[9];
    const void* Wattn  = d_in[10];
    const void* rela   = d_in[11];
    const void* w1     = d_in[12];
    const void* b1     = d_in[13];
    const void* w2     = d_in[14];
    const void* b2     = d_in[15];

    char* ws = (char*)d_ws;
    u16*   hs     = (u16*)ws;                        //  51,200,000 B
    float* wrq    = (float*)(ws +  51200000);        //     409,600 B
    u64*   slotsAL= (u64*) (ws +  51609600);         //  25,600,000 B (200k x 16 x 8B)
    int*   deg    = (int*) (ws +  77209600);         //     800,000 B
    u16*   WsH    = (u16*) (ws +  78009600);
    u16*   WsL    = (u16*) (ws +  78042368);
    u16*   w1H    = (u16*) (ws +  78075136);
    u16*   w1L    = (u16*) (ws +  78107904);
    u16*   w2H    = (u16*) (ws +  78140672);
    u16*   w2L    = (u16*) (ws +  78173440);
    float* b1f    = (float*)(ws +  78206208);
    float* b2f    = (float*)(ws +  78206720);
    float* wattnf = (float*)(ws +  78207232);
    float* relaf  = (float*)(ws +  78207744);        //     102,400 B
    int*   flag   = (int*) (ws +  78310144);

    int nE = in_sizes[4] / 4;

    k_probe<<<1, 64, 0, stream>>>((const u32*)query, flag);
    hipMemsetAsync(deg, 0, (size_t)BN * 4, stream);
    k_wprep<<<294, 256, 0, stream>>>(Ws, w1, w2, b1, b2, Wattn, rela,
                                     WsH, WsL, w1H, w1L, w2H, w2L,
                                     b1f, b2f, wattnf, relaf, flag);
    k_wrq<<<Bb * Rr, 128, 0, stream>>>(Wr, Wqr, Wqrb, rela, query, wrq, flag);
    k_hs<<<BN / 64, 256, 0, stream>>>(hidden, WsH, WsL, hs, flag);
    {
        long long thr = (long long)nE * 16;
        int blocks = (int)((thr + 255) / 256);
        k_alpha<<<blocks, 256, 0, stream>>>(edges, hs, wrq, wattnf, slotsAL, deg, nE);
    }
    k_fused<<<BN / 64, 256, 0, stream>>>(slotsAL, deg, hidden, relaf,
                                         w1H, w1L, w2H, w2L, b1f, b2f, d_out, flag);
}